// Round 6
// baseline (200.469 us; speedup 1.0000x reference)
//
#include <hip/hip_runtime.h>
#include <cstdint>
#include <cstddef>

// ---------------------------------------------------------------------------
// RandomCutoff: out = where(mask, log(f64 eps), x), x: (16, 25600, 256) f32.
// Mask comes from jax.random with FIXED seed 42 -> input-independent; we
// reproduce JAX's threefry2x32 (partitionable mode) bit-exactly.
// R1: nt load+store + full unroll, chunked blocks -> 152 us (5.5 TB/s eff.)
// R2: unroll-5                                    -> 155 us (not VGPR-bound)
// R3: hipMemcpyAsync blit + patch                 -> 170 us (blit slower)
// R4: nt load + regular store                     -> 163 us (nt store wins)
// R5: ALL mask params moved to COMPILE TIME (3328-entry constexpr table,
//     built in 13 chunks to stay under constexpr-step limits). Kernel is
//     now an exact copy-ubench replica: linear grid-stride, 2048x256,
//     50 compile-time iters, nt both ways. j = (i>>6)/100 indexes table.
// ---------------------------------------------------------------------------

#define T_TOT 25600
#define F_TOT 256
#define TSTEP 100
#define NJ 3328            // 13 channels * 256 time-blocks

static constexpr float LOG_EPS = -36.04365338911715f; // float32(log(f64 eps))

typedef float f32x4 __attribute__((ext_vector_type(4)));
typedef int   i32x4 __attribute__((ext_vector_type(4)));

struct U2 { unsigned a, b; };

__host__ __device__ constexpr unsigned rotl_(unsigned x, int d) {
  return (x << d) | (x >> (32 - d));
}

// Threefry-2x32, 20 rounds, exactly as JAX's reference implementation.
__host__ __device__ constexpr U2 tf(unsigned k0, unsigned k1, unsigned x0, unsigned x1) {
  const unsigned ks2 = k0 ^ k1 ^ 0x1BD11BDAu;
  x0 += k0; x1 += k1;
  x0 += x1; x1 = rotl_(x1,13) ^ x0;
  x0 += x1; x1 = rotl_(x1,15) ^ x0;
  x0 += x1; x1 = rotl_(x1,26) ^ x0;
  x0 += x1; x1 = rotl_(x1, 6) ^ x0;
  x0 += k1; x1 += ks2 + 1u;
  x0 += x1; x1 = rotl_(x1,17) ^ x0;
  x0 += x1; x1 = rotl_(x1,29) ^ x0;
  x0 += x1; x1 = rotl_(x1,16) ^ x0;
  x0 += x1; x1 = rotl_(x1,24) ^ x0;
  x0 += ks2; x1 += k0 + 2u;
  x0 += x1; x1 = rotl_(x1,13) ^ x0;
  x0 += x1; x1 = rotl_(x1,15) ^ x0;
  x0 += x1; x1 = rotl_(x1,26) ^ x0;
  x0 += x1; x1 = rotl_(x1, 6) ^ x0;
  x0 += k0; x1 += k1 + 3u;
  x0 += x1; x1 = rotl_(x1,17) ^ x0;
  x0 += x1; x1 = rotl_(x1,29) ^ x0;
  x0 += x1; x1 = rotl_(x1,16) ^ x0;
  x0 += x1; x1 = rotl_(x1,24) ^ x0;
  x0 += k1; x1 += ks2 + 4u;
  x0 += x1; x1 = rotl_(x1,13) ^ x0;
  x0 += x1; x1 = rotl_(x1,15) ^ x0;
  x0 += x1; x1 = rotl_(x1,26) ^ x0;
  x0 += x1; x1 = rotl_(x1, 6) ^ x0;
  x0 += ks2; x1 += k0 + 5u;
  return U2{x0, x1};
}

// ---- compile-time key tree (seed 42 -> key data (0,42)), partitionable ----
constexpr U2 KCOIN = tf(0u, 42u, 0u, 0u);
constexpr U2 KMASK = tf(0u, 42u, 0u, 1u);
constexpr U2 K1 = tf(KMASK.a, KMASK.b, 0u, 0u);
constexpr U2 K2 = tf(KMASK.a, KMASK.b, 0u, 1u);
constexpr U2 K3 = tf(KMASK.a, KMASK.b, 0u, 2u);
constexpr U2 K4 = tf(KMASK.a, KMASK.b, 0u, 3u);
constexpr U2 CE = tf(KCOIN.a, KCOIN.b, 0u, 0u);
constexpr unsigned COIN_BITS = CE.a ^ CE.b;
// uniform() <= 0.5  <=>  mantissa bits (bits>>9) <= 2^22  (exact, integer)
constexpr bool APPLY = (COIN_BITS >> 9) <= 4194304u;

// u01 = bitcast((bits>>9)|0x3f800000)-1 == (float)(bits>>9) * 2^-23  (exact)
__host__ __device__ constexpr float u01c(unsigned bits) {
  return (float)(bits >> 9) * (1.0f / 8388608.0f);
}

struct alignas(16) Quad { int ts, te, fs, fe; };

// Per (c, time-block) mask parameters: j = c*256 + b, j in [0, 3328).
// (int) truncation of a nonnegative float == floorf; float ops replicate
// the reference's f32 RN arithmetic exactly (verified bit-exact R1-R4).
__host__ __device__ constexpr Quad qcompute(int j) {
  const unsigned uj = (unsigned)j;
  U2 e = tf(K1.a, K1.b, 0u, uj);            unsigned h = e.a ^ e.b;
  e = tf(K1.a, K1.b, 0u, uj + 3328u);       unsigned l = e.a ^ e.b;
  const unsigned tl = ((h % 35u) * 11u + (l % 35u)) % 35u; // (2^16%35)^2%35=11
  e = tf(K2.a, K2.b, 0u, uj);               unsigned bits = e.a ^ e.b;
  const int tstart = (int)(u01c(bits) * (float)(TSTEP - (int)tl));
  e = tf(K3.a, K3.b, 0u, uj);               h = e.a ^ e.b;
  e = tf(K3.a, K3.b, 0u, uj + 3328u);       l = e.a ^ e.b;
  const unsigned fl = ((h % 30u) * 16u + (l % 30u)) % 30u; // (2^16%30)^2%30=16
  e = tf(K4.a, K4.b, 0u, uj);               bits = e.a ^ e.b;
  const int fstart = (int)(u01c(bits) * (float)(F_TOT - (int)fl));
  return Quad{tstart, tstart + (int)tl, fstart, fstart + (int)fl};
}

// Build the table in 13 per-channel chunks (~250K constexpr steps each,
// under clang's 1M step limit); then cheap concatenation.
struct ChunkT { Quad q[256]; };
template <int C>
constexpr ChunkT mkc() {
  ChunkT t{};
  for (int b = 0; b < 256; ++b) t.q[b] = qcompute(C * 256 + b);
  return t;
}
constexpr ChunkT TC0 = mkc<0>();  constexpr ChunkT TC1 = mkc<1>();
constexpr ChunkT TC2 = mkc<2>();  constexpr ChunkT TC3 = mkc<3>();
constexpr ChunkT TC4 = mkc<4>();  constexpr ChunkT TC5 = mkc<5>();
constexpr ChunkT TC6 = mkc<6>();  constexpr ChunkT TC7 = mkc<7>();
constexpr ChunkT TC8 = mkc<8>();  constexpr ChunkT TC9 = mkc<9>();
constexpr ChunkT TC10 = mkc<10>(); constexpr ChunkT TC11 = mkc<11>();
constexpr ChunkT TC12 = mkc<12>();

struct AllT { Quad q[NJ]; };
constexpr AllT mkall() {
  AllT a{};
  const ChunkT* cs[13] = {&TC0,&TC1,&TC2,&TC3,&TC4,&TC5,&TC6,&TC7,&TC8,&TC9,&TC10,&TC11,&TC12};
  for (int c = 0; c < 13; ++c)
    for (int b = 0; b < 256; ++b) a.q[c * 256 + b] = cs[c]->q[b];
  return a;
}
__device__ const AllT PTAB = mkall();

// Copy-ubench replica: linear grid-stride, 2048 blocks x 256 threads,
// exactly 50 iterations/thread (26,214,400 float4 total). Each wave covers
// one 256-float row per iteration -> all mask branches wave-uniform.
// row = i>>6; j = row/100 (magic mul) indexes the 53KB param table.
#define NTHREADS (2048 * 256)
__global__ void __launch_bounds__(256)
speca_kernel(const float* __restrict__ x, float* __restrict__ y) {
  const int tid = (int)(blockIdx.x * 256 + threadIdx.x);
  const f32x4* __restrict__ in4 = (const f32x4*)x;
  f32x4* __restrict__ o4 = (f32x4*)y;
  const int f0 = (tid & 63) << 2;          // invariant: stride % 64 == 0
  const unsigned base_row = (unsigned)tid >> 6;
#pragma unroll 10
  for (int k = 0; k < 50; ++k) {
    const int i = tid + k * NTHREADS;
    f32x4 v = __builtin_nontemporal_load(&in4[i]);
    const unsigned row = base_row + (unsigned)k * (NTHREADS / 64);
    const unsigned j = row / 100u;         // = c*256 + b  (magic mul)
    const int r = (int)(row - j * 100u);   // local t in chunk
    if (APPLY && j < (unsigned)NJ) {       // j<3328 <=> c<13; wave-uniform
      const i32x4 q = *(const i32x4*)&PTAB.q[j];   // ts,te,fs,fe (16B, cached)
      if (r >= q[0] && r < q[1]) {         // wave-uniform
        if (f0     >= q[2] && f0     < q[3]) v[0] = LOG_EPS;
        if (f0 + 1 >= q[2] && f0 + 1 < q[3]) v[1] = LOG_EPS;
        if (f0 + 2 >= q[2] && f0 + 2 < q[3]) v[2] = LOG_EPS;
        if (f0 + 3 >= q[2] && f0 + 3 < q[3]) v[3] = LOG_EPS;
      }
    }
    __builtin_nontemporal_store(v, &o4[i]);
  }
}

extern "C" void kernel_launch(void* const* d_in, const int* in_sizes, int n_in,
                              void* d_out, int out_size, void* d_ws, size_t ws_size,
                              hipStream_t stream) {
  const float* x = (const float*)d_in[0];
  float* y = (float*)d_out;
  hipLaunchKernelGGL(speca_kernel, dim3(2048), dim3(256), 0, stream, x, y);
}

// Round 7
// 152.401 us; speedup vs baseline: 1.3154x; 1.3154x over previous
//
#include <hip/hip_runtime.h>
#include <cstdint>
#include <cstddef>

// ---------------------------------------------------------------------------
// RandomCutoff: out = where(mask, log(f64 eps), x), x: (16, 25600, 256) f32.
// Mask comes from jax.random with FIXED seed 42 -> input-independent; we
// reproduce JAX's threefry2x32 (partitionable mode) bit-exactly.
// R1: nt load+store + full unroll, chunked blocks -> 152 us (5.5 TB/s eff.)
// R2: unroll-5                                    -> 155 us (not VGPR-bound)
// R3: hipMemcpyAsync blit + patch                 -> 170 us (blit slower)
// R4: nt load + regular store                     -> 163 us (nt store wins)
// R5: grid-stride + per-iter table load           -> 200 us (2 vars changed;
//     dependent VMEM load per iter serializes the stream. Bad A/B.)
// R6: R1 structure EXACTLY + compile-time param table read once per block
//     at a wave-uniform address (s_load_dwordx4). Single-variable test of
//     the threefry prologue. If neutral -> declare roofline at R1/R6.
// ---------------------------------------------------------------------------

#define C_TOT 16
#define C_MASKED 13
#define T_TOT 25600
#define F_TOT 256
#define NB 256          // T / 100 time blocks
#define TSTEP 100
#define NJ 3328         // 13 * 256

static constexpr float LOG_EPS = -36.04365338911715f; // float32(log(f64 eps))

typedef float f32x4 __attribute__((ext_vector_type(4)));

struct U2 { unsigned a, b; };

__host__ __device__ constexpr unsigned rotl_(unsigned x, int d) {
  return (x << d) | (x >> (32 - d));
}

// Threefry-2x32, 20 rounds, exactly as JAX's reference implementation.
__host__ __device__ constexpr U2 tf(unsigned k0, unsigned k1, unsigned x0, unsigned x1) {
  const unsigned ks2 = k0 ^ k1 ^ 0x1BD11BDAu;
  x0 += k0; x1 += k1;
  x0 += x1; x1 = rotl_(x1,13) ^ x0;
  x0 += x1; x1 = rotl_(x1,15) ^ x0;
  x0 += x1; x1 = rotl_(x1,26) ^ x0;
  x0 += x1; x1 = rotl_(x1, 6) ^ x0;
  x0 += k1; x1 += ks2 + 1u;
  x0 += x1; x1 = rotl_(x1,17) ^ x0;
  x0 += x1; x1 = rotl_(x1,29) ^ x0;
  x0 += x1; x1 = rotl_(x1,16) ^ x0;
  x0 += x1; x1 = rotl_(x1,24) ^ x0;
  x0 += ks2; x1 += k0 + 2u;
  x0 += x1; x1 = rotl_(x1,13) ^ x0;
  x0 += x1; x1 = rotl_(x1,15) ^ x0;
  x0 += x1; x1 = rotl_(x1,26) ^ x0;
  x0 += x1; x1 = rotl_(x1, 6) ^ x0;
  x0 += k0; x1 += k1 + 3u;
  x0 += x1; x1 = rotl_(x1,17) ^ x0;
  x0 += x1; x1 = rotl_(x1,29) ^ x0;
  x0 += x1; x1 = rotl_(x1,16) ^ x0;
  x0 += x1; x1 = rotl_(x1,24) ^ x0;
  x0 += k1; x1 += ks2 + 4u;
  x0 += x1; x1 = rotl_(x1,13) ^ x0;
  x0 += x1; x1 = rotl_(x1,15) ^ x0;
  x0 += x1; x1 = rotl_(x1,26) ^ x0;
  x0 += x1; x1 = rotl_(x1, 6) ^ x0;
  x0 += ks2; x1 += k0 + 5u;
  return U2{x0, x1};
}

// ---- compile-time key tree (seed 42 -> key data (0,42)), partitionable ----
constexpr U2 KCOIN = tf(0u, 42u, 0u, 0u);
constexpr U2 KMASK = tf(0u, 42u, 0u, 1u);
constexpr U2 K1 = tf(KMASK.a, KMASK.b, 0u, 0u);
constexpr U2 K2 = tf(KMASK.a, KMASK.b, 0u, 1u);
constexpr U2 K3 = tf(KMASK.a, KMASK.b, 0u, 2u);
constexpr U2 K4 = tf(KMASK.a, KMASK.b, 0u, 3u);
constexpr U2 CE = tf(KCOIN.a, KCOIN.b, 0u, 0u);
constexpr unsigned COIN_BITS = CE.a ^ CE.b;
// uniform() <= 0.5  <=>  mantissa bits (bits>>9) <= 2^22  (exact, integer)
constexpr bool APPLY = (COIN_BITS >> 9) <= 4194304u;

// u01 = bitcast((bits>>9)|0x3f800000)-1 == (float)(bits>>9) * 2^-23  (exact)
__host__ __device__ constexpr float u01c(unsigned bits) {
  return (float)(bits >> 9) * (1.0f / 8388608.0f);
}

struct alignas(16) Quad { int ts, te, fs, fe; };

// Per (c, time-block) mask parameters: j = c*256 + b, j in [0, 3328).
// (int) truncation of nonnegative float == floorf; f32 RN arithmetic matches
// the reference exactly (verified bit-exact R1-R6: absmax always 0).
__host__ __device__ constexpr Quad qcompute(int j) {
  const unsigned uj = (unsigned)j;
  U2 e = tf(K1.a, K1.b, 0u, uj);            unsigned h = e.a ^ e.b;
  e = tf(K1.a, K1.b, 0u, uj + 3328u);       unsigned l = e.a ^ e.b;
  const unsigned tl = ((h % 35u) * 11u + (l % 35u)) % 35u; // (2^16%35)^2%35=11
  e = tf(K2.a, K2.b, 0u, uj);               unsigned bits = e.a ^ e.b;
  const int tstart = (int)(u01c(bits) * (float)(TSTEP - (int)tl));
  e = tf(K3.a, K3.b, 0u, uj);               h = e.a ^ e.b;
  e = tf(K3.a, K3.b, 0u, uj + 3328u);       l = e.a ^ e.b;
  const unsigned fl = ((h % 30u) * 16u + (l % 30u)) % 30u; // (2^16%30)^2%30=16
  e = tf(K4.a, K4.b, 0u, uj);               bits = e.a ^ e.b;
  const int fstart = (int)(u01c(bits) * (float)(F_TOT - (int)fl));
  return Quad{tstart, tstart + (int)tl, fstart, fstart + (int)fl};
}

// Build the table in 13 per-channel chunks to stay under constexpr limits.
struct ChunkT { Quad q[256]; };
template <int C>
constexpr ChunkT mkc() {
  ChunkT t{};
  for (int b = 0; b < 256; ++b) t.q[b] = qcompute(C * 256 + b);
  return t;
}
constexpr ChunkT TC0 = mkc<0>();  constexpr ChunkT TC1 = mkc<1>();
constexpr ChunkT TC2 = mkc<2>();  constexpr ChunkT TC3 = mkc<3>();
constexpr ChunkT TC4 = mkc<4>();  constexpr ChunkT TC5 = mkc<5>();
constexpr ChunkT TC6 = mkc<6>();  constexpr ChunkT TC7 = mkc<7>();
constexpr ChunkT TC8 = mkc<8>();  constexpr ChunkT TC9 = mkc<9>();
constexpr ChunkT TC10 = mkc<10>(); constexpr ChunkT TC11 = mkc<11>();
constexpr ChunkT TC12 = mkc<12>();

struct AllT { Quad q[NJ]; };
constexpr AllT mkall() {
  AllT a{};
  const ChunkT* cs[13] = {&TC0,&TC1,&TC2,&TC3,&TC4,&TC5,&TC6,&TC7,&TC8,&TC9,&TC10,&TC11,&TC12};
  for (int c = 0; c < 13; ++c)
    for (int b = 0; b < 256; ++b) a.q[c * 256 + b] = cs[c]->q[b];
  return a;
}
__device__ const AllT PTAB = mkall();

// R1 structure: one block per (c, time-block) chunk, 100x256 floats =
// 6400 f4 = 25 fully-unrolled iterations of 256 threads, nt load + nt store.
// Mask params come from ONE wave-uniform s_load at block entry (vs R1's
// ~540-cycle serial threefry prologue; vs R5's per-iteration VMEM load).
__global__ void __launch_bounds__(256)
speca_kernel(const float* __restrict__ x, float* __restrict__ y) {
  const int bid = blockIdx.x;
  const int c = bid >> 8;          // 0..15
  const int b = bid & 255;         // 0..255
  const size_t base = ((size_t)c * T_TOT + (size_t)b * TSTEP) * F_TOT;
  const f32x4* __restrict__ in4 = (const f32x4*)(x + base);
  f32x4* __restrict__ o4 = (f32x4*)(y + base);

  int ts = 0, te = -1, fs = 0, fe = -1;
  if (APPLY && bid < NJ) {         // bid < 3328 <=> c < 13; uniform branch
    const Quad q = PTAB.q[bid];    // uniform address -> s_load_dwordx4
    ts = q.ts; te = q.te; fs = q.fs; fe = q.fe;
  }

  const int tid = (int)threadIdx.x;
#pragma unroll
  for (int k = 0; k < (TSTEP * F_TOT) / 4 / 256; ++k) {   // 25
    const int i = k * 256 + tid;
    f32x4 v = __builtin_nontemporal_load(&in4[i]);
    const int r = i >> 6;                    // local t within chunk (0..99)
    if (r >= ts && r < te) {                 // wave-uniform (64 f4 = one row)
      const int f0 = (i & 63) << 2;
      if (f0     >= fs && f0     < fe) v[0] = LOG_EPS;
      if (f0 + 1 >= fs && f0 + 1 < fe) v[1] = LOG_EPS;
      if (f0 + 2 >= fs && f0 + 2 < fe) v[2] = LOG_EPS;
      if (f0 + 3 >= fs && f0 + 3 < fe) v[3] = LOG_EPS;
    }
    __builtin_nontemporal_store(v, &o4[i]);
  }
}

extern "C" void kernel_launch(void* const* d_in, const int* in_sizes, int n_in,
                              void* d_out, int out_size, void* d_ws, size_t ws_size,
                              hipStream_t stream) {
  const float* x = (const float*)d_in[0];
  float* y = (float*)d_out;
  // 16 channels * 256 time-blocks = 4096 blocks
  hipLaunchKernelGGL(speca_kernel, dim3(C_TOT * NB), dim3(256), 0, stream, x, y);
}